// Round 1
// baseline (1114.041 us; speedup 1.0000x reference)
//
#include <hip/hip_runtime.h>

// Problem constants (B=4, S=2048, H=1024, E=8, F=4096, K=2)
#define T_TOKENS 8192
#define H_DIM 1024
#define E_EXP 8
#define F_DIM 4096
#define CAP 8192   // max tokens routable to one expert (top-2 distinct => <= T)

typedef __attribute__((ext_vector_type(8))) short short8;
typedef __attribute__((ext_vector_type(4))) float f32x4;

__device__ __forceinline__ unsigned short f2bf(float f) {
    unsigned int u = __float_as_uint(f);
    u += 0x7fffu + ((u >> 16) & 1u);   // round-to-nearest-even
    return (unsigned short)(u >> 16);
}

__device__ __forceinline__ float gelu_tanh(float x) {
    // jax.nn.gelu default (approximate=True): 0.5x(1+tanh(sqrt(2/pi)(x+0.044715x^3)))
    float z = 0.7978845608028654f * (x + 0.044715f * x * x * x);
    float t = 1.0f - 2.0f / (__expf(2.0f * z) + 1.0f);   // tanh(z)
    return 0.5f * x * (1.0f + t);
}

// ---------------- router: top-2 + softmax over the 2 selected ----------------
__global__ void router_kernel(const float* __restrict__ logits,
                              int* __restrict__ cnt,
                              int* __restrict__ tok,
                              float* __restrict__ wt) {
    int t = blockIdx.x * 256 + threadIdx.x;
    if (t >= T_TOKENS) return;
    float l[E_EXP];
#pragma unroll
    for (int i = 0; i < E_EXP; i++) l[i] = logits[t * E_EXP + i];
    int i0 = 0; float s0 = l[0];
#pragma unroll
    for (int i = 1; i < E_EXP; i++) if (l[i] > s0) { s0 = l[i]; i0 = i; }
    int i1 = (i0 == 0) ? 1 : 0; float s1 = l[i1];
#pragma unroll
    for (int i = 0; i < E_EXP; i++) if (i != i0 && l[i] > s1) { s1 = l[i]; i1 = i; }
    float p0 = 1.0f / (1.0f + __expf(s1 - s0));
    float p1 = 1.0f - p0;
    int sl0 = atomicAdd(&cnt[i0], 1);
    tok[i0 * CAP + sl0] = t; wt[i0 * CAP + sl0] = p0;
    int sl1 = atomicAdd(&cnt[i1], 1);
    tok[i1 * CAP + sl1] = t; wt[i1 * CAP + sl1] = p1;
}

__global__ void base_kernel(const int* __restrict__ cnt, int* __restrict__ base) {
    if (threadIdx.x == 0) {
        int b = 0;
        for (int e = 0; e < E_EXP; e++) { base[e] = b; b += cnt[e]; }
    }
}

// ---------------- x fp32 -> bf16 ----------------
__global__ void cvtx_kernel(const float* __restrict__ x, unsigned short* __restrict__ xg) {
    int i = blockIdx.x * 256 + threadIdx.x;   // over T*H/4
    float4 v = ((const float4*)x)[i];
    ushort4 o;
    o.x = f2bf(v.x); o.y = f2bf(v.y); o.z = f2bf(v.z); o.w = f2bf(v.w);
    ((ushort4*)xg)[i] = o;
}

// ---------------- transpose + convert: in [M,N] fp32 -> out [N,M] bf16 (per expert z)
__global__ void tcvt_kernel(const float* __restrict__ in, unsigned short* __restrict__ out,
                            int M, int N) {
    __shared__ float t[64][65];
    size_t eoff = (size_t)blockIdx.z * M * N;
    in += eoff; out += eoff;
    int r0 = blockIdx.x * 64, c0 = blockIdx.y * 64;
    int tid = threadIdx.x;
    int rr = tid >> 4;        // 0..15
    int cl = tid & 15;        // 0..15
#pragma unroll
    for (int p = 0; p < 4; p++) {
        int row = p * 16 + rr;
        float4 v = *(const float4*)&in[(size_t)(r0 + row) * N + c0 + cl * 4];
        t[row][cl * 4 + 0] = v.x; t[row][cl * 4 + 1] = v.y;
        t[row][cl * 4 + 2] = v.z; t[row][cl * 4 + 3] = v.w;
    }
    __syncthreads();
#pragma unroll
    for (int p = 0; p < 4; p++) {
        int orow = p * 16 + rr;   // local n index
        ushort4 o;
        o.x = f2bf(t[cl * 4 + 0][orow]);
        o.y = f2bf(t[cl * 4 + 1][orow]);
        o.z = f2bf(t[cl * 4 + 2][orow]);
        o.w = f2bf(t[cl * 4 + 3][orow]);
        *(ushort4*)&out[(size_t)(c0 + orow) * M + r0 + cl * 4] = o;
    }
}

// ---------------- grouped GEMM ----------------
// C[m,n] = sum_k A[m,k] * B[n,k]   (B pre-transposed, k contiguous)
// GATHER=1: A row m of expert e is xg[tok[e*CAP+m]]     (GEMM1)
// GATHER=0: A row m of expert e is G[base[e]+m]         (GEMM2)
// EPI=0: gelu -> bf16 G[(base+m)*N + n]
// EPI=1: atomicAdd(out[tok*N + n], wt * val)
template <int GATHER, int EPI>
__global__ __launch_bounds__(256, 2)
void gemm_kernel(const unsigned short* __restrict__ Asrc,
                 const unsigned short* __restrict__ Bt,
                 int K, int N,
                 const int* __restrict__ cnt, const int* __restrict__ base,
                 const int* __restrict__ tok, const float* __restrict__ wt,
                 unsigned short* __restrict__ Gout, float* __restrict__ out) {
    const int e = blockIdx.z;
    const int cnt_e = cnt[e];
    const int m0 = blockIdx.x * 128;
    if (m0 >= cnt_e) return;
    const int base_e = base[e];
    const int n0 = blockIdx.y * 128;
    const int tid = threadIdx.x;
    const int lane = tid & 63;
    const int wave = tid >> 6;
    const int quad = lane >> 4, l16 = lane & 15;
    const int wm = (wave & 1) * 64, wn = (wave >> 1) * 64;

    __shared__ unsigned short As[128 * 40];   // 128 rows x 32 k, stride 40 (pad)
    __shared__ unsigned short Bs[128 * 40];

    // staging: 256 threads, 2 rounds; thread covers (row = p*64 + tid/4, 8 elems at (tid%4)*8)
    const int srow = tid >> 2;
    const int scol = (tid & 3) * 8;
    const unsigned short* a_base[2];
    const unsigned short* b_base[2];
#pragma unroll
    for (int p = 0; p < 2; p++) {
        int r = p * 64 + srow;
        int gr = m0 + r; if (gr > cnt_e - 1) gr = cnt_e - 1;   // clamp tail (guarded in epilogue)
        if (GATHER) {
            int tk = tok[e * CAP + gr];
            a_base[p] = Asrc + (size_t)tk * K + scol;
        } else {
            a_base[p] = Asrc + (size_t)(base_e + gr) * K + scol;
        }
        b_base[p] = Bt + (size_t)e * (size_t)N * K + (size_t)(n0 + r) * K + scol;
    }

    f32x4 acc[4][4];
#pragma unroll
    for (int i = 0; i < 4; i++)
#pragma unroll
        for (int j = 0; j < 4; j++) acc[i][j] = (f32x4){0.f, 0.f, 0.f, 0.f};

    for (int k0 = 0; k0 < K; k0 += 32) {
#pragma unroll
        for (int p = 0; p < 2; p++) {
            uint4 av = *(const uint4*)(a_base[p] + k0);
            uint4 bv = *(const uint4*)(b_base[p] + k0);
            *(uint4*)&As[(p * 64 + srow) * 40 + scol] = av;
            *(uint4*)&Bs[(p * 64 + srow) * 40 + scol] = bv;
        }
        __syncthreads();
        short8 af[4], bf[4];
#pragma unroll
        for (int i = 0; i < 4; i++)
            af[i] = *(const short8*)&As[(wm + i * 16 + l16) * 40 + quad * 8];
#pragma unroll
        for (int j = 0; j < 4; j++)
            bf[j] = *(const short8*)&Bs[(wn + j * 16 + l16) * 40 + quad * 8];
#pragma unroll
        for (int i = 0; i < 4; i++)
#pragma unroll
            for (int j = 0; j < 4; j++)
                acc[i][j] = __builtin_amdgcn_mfma_f32_16x16x32_bf16(af[i], bf[j], acc[i][j], 0, 0, 0);
        __syncthreads();
    }

    // epilogue: D row = quad*4 + reg, D col = l16 (within each 16x16 tile)
    if (EPI == 0) {
#pragma unroll
        for (int i = 0; i < 4; i++) {
            int lm = wm + i * 16 + quad * 4;
#pragma unroll
            for (int r = 0; r < 4; r++) {
                int gr = m0 + lm + r;
                if (gr < cnt_e) {
                    size_t rowoff = (size_t)(base_e + gr) * N;
#pragma unroll
                    for (int j = 0; j < 4; j++) {
                        int ncol = n0 + wn + j * 16 + l16;
                        Gout[rowoff + ncol] = f2bf(gelu_tanh(acc[i][j][r]));
                    }
                }
            }
        }
    } else {
#pragma unroll
        for (int i = 0; i < 4; i++) {
            int lm = wm + i * 16 + quad * 4;
#pragma unroll
            for (int r = 0; r < 4; r++) {
                int gr = m0 + lm + r;
                if (gr < cnt_e) {
                    int tk = tok[e * CAP + gr];
                    float w = wt[e * CAP + gr];
                    float* orow = out + (size_t)tk * N;
#pragma unroll
                    for (int j = 0; j < 4; j++) {
                        int ncol = n0 + wn + j * 16 + l16;
                        atomicAdd(&orow[ncol], w * acc[i][j][r]);
                    }
                }
            }
        }
    }
}

extern "C" void kernel_launch(void* const* d_in, const int* in_sizes, int n_in,
                              void* d_out, int out_size, void* d_ws, size_t ws_size,
                              hipStream_t stream) {
    const float* x      = (const float*)d_in[0];
    const float* logits = (const float*)d_in[1];
    const float* w1     = (const float*)d_in[2];
    const float* w2     = (const float*)d_in[3];
    float* out = (float*)d_out;
    char* ws = (char*)d_ws;

    // workspace layout
    const size_t OFF_CNT  = 0;
    const size_t OFF_BASE = 64;
    const size_t OFF_TOK  = 1024;
    const size_t OFF_WT   = OFF_TOK + (size_t)E_EXP * CAP * 4;                 // 263168
    const size_t OFF_XG   = 1u << 20;                                          // 1 MiB
    const size_t OFF_W1T  = OFF_XG + (size_t)T_TOKENS * H_DIM * 2;             // +16 MiB
    const size_t OFF_W2T  = OFF_W1T + (size_t)E_EXP * H_DIM * F_DIM * 2;       // +64 MiB
    const size_t OFF_G    = OFF_W2T + (size_t)E_EXP * H_DIM * F_DIM * 2;       // +64 MiB
    // total = OFF_G + 16384*4096*2 = ~273 MiB

    int* cnt  = (int*)(ws + OFF_CNT);
    int* base = (int*)(ws + OFF_BASE);
    int* tok  = (int*)(ws + OFF_TOK);
    float* wt = (float*)(ws + OFF_WT);
    unsigned short* xg  = (unsigned short*)(ws + OFF_XG);
    unsigned short* w1t = (unsigned short*)(ws + OFF_W1T);
    unsigned short* w2t = (unsigned short*)(ws + OFF_W2T);
    unsigned short* G   = (unsigned short*)(ws + OFF_G);

    hipMemsetAsync(d_out, 0, (size_t)out_size * sizeof(float), stream);
    hipMemsetAsync(cnt, 0, 64, stream);

    router_kernel<<<T_TOKENS / 256, 256, 0, stream>>>(logits, cnt, tok, wt);
    base_kernel<<<1, 64, 0, stream>>>(cnt, base);
    cvtx_kernel<<<(T_TOKENS * H_DIM / 4) / 256, 256, 0, stream>>>(x, xg);
    // w1 [E,H,F] -> w1t [E,F,H]
    tcvt_kernel<<<dim3(H_DIM / 64, F_DIM / 64, E_EXP), 256, 0, stream>>>(w1, w1t, H_DIM, F_DIM);
    // w2 [E,F,H] -> w2t [E,H,F]
    tcvt_kernel<<<dim3(F_DIM / 64, H_DIM / 64, E_EXP), 256, 0, stream>>>(w2, w2t, F_DIM, H_DIM);
    // GEMM1: [cnt_e x 1024] @ w1t -> gelu -> G [cnt_e x 4096] bf16
    gemm_kernel<1, 0><<<dim3(CAP / 128, F_DIM / 128, E_EXP), 256, 0, stream>>>(
        xg, w1t, H_DIM, F_DIM, cnt, base, tok, wt, G, nullptr);
    // GEMM2: G @ w2t -> weighted scatter-add into out
    gemm_kernel<0, 1><<<dim3(CAP / 128, H_DIM / 128, E_EXP), 256, 0, stream>>>(
        G, w2t, F_DIM, H_DIM, cnt, base, tok, wt, nullptr, out);
    (void)in_sizes; (void)n_in; (void)ws_size;
}

// Round 2
// 1040.824 us; speedup vs baseline: 1.0703x; 1.0703x over previous
//
#include <hip/hip_runtime.h>

// Problem constants (B=4, S=2048, H=1024, E=8, F=4096, K=2)
#define T_TOKENS 8192
#define H_DIM 1024
#define E_EXP 8
#define F_DIM 4096
#define CAP 8192   // max tokens routable to one expert (top-2 distinct => <= T)

typedef __attribute__((ext_vector_type(8))) short short8;
typedef __attribute__((ext_vector_type(4))) float f32x4;

__device__ __forceinline__ unsigned short f2bf(float f) {
    unsigned int u = __float_as_uint(f);
    u += 0x7fffu + ((u >> 16) & 1u);   // round-to-nearest-even
    return (unsigned short)(u >> 16);
}

__device__ __forceinline__ float gelu_tanh(float x) {
    // jax.nn.gelu default (approximate=True)
    float z = 0.7978845608028654f * (x + 0.044715f * x * x * x);
    float t = 1.0f - 2.0f / (__expf(2.0f * z) + 1.0f);   // tanh(z)
    return 0.5f * x * (1.0f + t);
}

// async 16B global->LDS DMA (lane i of the wave lands at ldsbase + i*16)
__device__ __forceinline__ void gld16(const void* g, void* l) {
    __builtin_amdgcn_global_load_lds(
        (const __attribute__((address_space(1))) unsigned int*)g,
        (__attribute__((address_space(3))) unsigned int*)l,
        16, 0, 0);
}

// ---------------- router: top-2 + softmax over the 2 selected ----------------
__global__ void router_kernel(const float* __restrict__ logits,
                              int* __restrict__ cnt,
                              int* __restrict__ tok,
                              float* __restrict__ wt) {
    int t = blockIdx.x * 256 + threadIdx.x;
    if (t >= T_TOKENS) return;
    float l[E_EXP];
#pragma unroll
    for (int i = 0; i < E_EXP; i++) l[i] = logits[t * E_EXP + i];
    int i0 = 0; float s0 = l[0];
#pragma unroll
    for (int i = 1; i < E_EXP; i++) if (l[i] > s0) { s0 = l[i]; i0 = i; }
    int i1 = (i0 == 0) ? 1 : 0; float s1 = l[i1];
#pragma unroll
    for (int i = 0; i < E_EXP; i++) if (i != i0 && l[i] > s1) { s1 = l[i]; i1 = i; }
    float p0 = 1.0f / (1.0f + __expf(s1 - s0));
    float p1 = 1.0f - p0;
    int sl0 = atomicAdd(&cnt[i0], 1);
    tok[i0 * CAP + sl0] = t; wt[i0 * CAP + sl0] = p0;
    int sl1 = atomicAdd(&cnt[i1], 1);
    tok[i1 * CAP + sl1] = t; wt[i1 * CAP + sl1] = p1;
}

__global__ void base_kernel(const int* __restrict__ cnt, int* __restrict__ base) {
    if (threadIdx.x == 0) {
        int b = 0;
        for (int e = 0; e < E_EXP; e++) { base[e] = b; b += cnt[e]; }
    }
}

// ---------------- x fp32 -> bf16 ----------------
__global__ void cvtx_kernel(const float* __restrict__ x, unsigned short* __restrict__ xg) {
    int i = blockIdx.x * 256 + threadIdx.x;   // over T*H/4
    float4 v = ((const float4*)x)[i];
    ushort4 o;
    o.x = f2bf(v.x); o.y = f2bf(v.y); o.z = f2bf(v.z); o.w = f2bf(v.w);
    ((ushort4*)xg)[i] = o;
}

// ---------------- transpose + convert: in [M,N] fp32 -> out [N,M] bf16 (per expert z)
__global__ void tcvt_kernel(const float* __restrict__ in, unsigned short* __restrict__ out,
                            int M, int N) {
    __shared__ float t[64][65];
    size_t eoff = (size_t)blockIdx.z * M * N;
    in += eoff; out += eoff;
    int r0 = blockIdx.x * 64, c0 = blockIdx.y * 64;
    int tid = threadIdx.x;
    int rr = tid >> 4;        // 0..15
    int cl = tid & 15;        // 0..15
#pragma unroll
    for (int p = 0; p < 4; p++) {
        int row = p * 16 + rr;
        float4 v = *(const float4*)&in[(size_t)(r0 + row) * N + c0 + cl * 4];
        t[row][cl * 4 + 0] = v.x; t[row][cl * 4 + 1] = v.y;
        t[row][cl * 4 + 2] = v.z; t[row][cl * 4 + 3] = v.w;
    }
    __syncthreads();
#pragma unroll
    for (int p = 0; p < 4; p++) {
        int orow = p * 16 + rr;   // local n index
        ushort4 o;
        o.x = f2bf(t[cl * 4 + 0][orow]);
        o.y = f2bf(t[cl * 4 + 1][orow]);
        o.z = f2bf(t[cl * 4 + 2][orow]);
        o.w = f2bf(t[cl * 4 + 3][orow]);
        *(ushort4*)&out[(size_t)(c0 + orow) * M + r0 + cl * 4] = o;
    }
}

// ---------------- grouped GEMM (m97-style: global_load_lds staging) ----------------
// C[m,n] = sum_k A[m,k] * B[n,k]   (B pre-transposed, k contiguous)
// GATHER=1: A row m of expert e is xg[tok[e*CAP+m]]     (GEMM1)
// GATHER=0: A row m of expert e is G[base[e]+m]         (GEMM2)
// EPI=0: gelu -> bf16 G[(base+m)*N + n]
// EPI=1: atomicAdd(out[tok*N + n], wt * val)
template <int GATHER, int EPI>
__global__ __launch_bounds__(256, 2)
void gemm_kernel(const unsigned short* __restrict__ Asrc,
                 const unsigned short* __restrict__ Bt,
                 int K, int N,
                 const int* __restrict__ cnt, const int* __restrict__ base,
                 const int* __restrict__ tok, const float* __restrict__ wt,
                 unsigned short* __restrict__ Gout, float* __restrict__ out) {
    const int e = blockIdx.z;
    const int cnt_e = cnt[e];
    const int m0 = blockIdx.x * 128;
    if (m0 >= cnt_e) return;
    const int base_e = base[e];
    const int n0 = blockIdx.y * 128;
    const int tid = threadIdx.x;
    const int lane = tid & 63;
    const int wave = tid >> 6;
    const int quad = lane >> 4, l16 = lane & 15;
    const int wm = (wave & 1) * 64, wn = (wave >> 1) * 64;

    // unpadded: row = 32 bf16 = 64 B; wave DMA = 16 rows (lane l -> row l/4, byte (l&3)*16)
    __shared__ unsigned short As[128 * 32];
    __shared__ unsigned short Bs[128 * 32];

    const int srow_in_issue = wave * 16 + (lane >> 2);   // 0..63 within issue
    const int selem = (lane & 3) * 8;                    // element offset within row (bf16)
    const unsigned short* aptr[2];
    const unsigned short* bptr[2];
    unsigned short* alds[2];
    unsigned short* blds[2];
#pragma unroll
    for (int p = 0; p < 2; p++) {
        int r = p * 64 + srow_in_issue;
        int gr = m0 + r; if (gr > cnt_e - 1) gr = cnt_e - 1;   // tail clamp (epilogue guards)
        const unsigned short* arow;
        if (GATHER) arow = Asrc + (size_t)tok[e * CAP + gr] * K;
        else        arow = Asrc + (size_t)(base_e + gr) * K;
        aptr[p] = arow + selem;
        bptr[p] = Bt + (size_t)e * (size_t)N * K + (size_t)(n0 + r) * K + selem;
        alds[p] = &As[(p * 64 + wave * 16) * 32];   // wave-uniform LDS base
        blds[p] = &Bs[(p * 64 + wave * 16) * 32];
    }

    f32x4 acc[4][4];
#pragma unroll
    for (int i = 0; i < 4; i++)
#pragma unroll
        for (int j = 0; j < 4; j++) acc[i][j] = (f32x4){0.f, 0.f, 0.f, 0.f};

    for (int k0 = 0; k0 < K; k0 += 32) {
#pragma unroll
        for (int p = 0; p < 2; p++) {
            gld16(aptr[p] + k0, alds[p]);
            gld16(bptr[p] + k0, blds[p]);
        }
        __syncthreads();   // compiler emits vmcnt(0) drain before s_barrier
        short8 af[4], bf[4];
#pragma unroll
        for (int i = 0; i < 4; i++)
            af[i] = *(const short8*)&As[(wm + i * 16 + l16) * 32 + quad * 8];
#pragma unroll
        for (int j = 0; j < 4; j++)
            bf[j] = *(const short8*)&Bs[(wn + j * 16 + l16) * 32 + quad * 8];
#pragma unroll
        for (int i = 0; i < 4; i++)
#pragma unroll
            for (int j = 0; j < 4; j++)
                acc[i][j] = __builtin_amdgcn_mfma_f32_16x16x32_bf16(af[i], bf[j], acc[i][j], 0, 0, 0);
        __syncthreads();
    }

    // epilogue: D row = quad*4 + reg, D col = l16 (within each 16x16 tile)
    if (EPI == 0) {
#pragma unroll
        for (int i = 0; i < 4; i++) {
            int lm = wm + i * 16 + quad * 4;
#pragma unroll
            for (int r = 0; r < 4; r++) {
                int gr = m0 + lm + r;
                if (gr < cnt_e) {
                    size_t rowoff = (size_t)(base_e + gr) * N;
#pragma unroll
                    for (int j = 0; j < 4; j++) {
                        int ncol = n0 + wn + j * 16 + l16;
                        Gout[rowoff + ncol] = f2bf(gelu_tanh(acc[i][j][r]));
                    }
                }
            }
        }
    } else {
#pragma unroll
        for (int i = 0; i < 4; i++) {
            int lm = wm + i * 16 + quad * 4;
#pragma unroll
            for (int r = 0; r < 4; r++) {
                int gr = m0 + lm + r;
                if (gr < cnt_e) {
                    int tk = tok[e * CAP + gr];
                    float w = wt[e * CAP + gr];
                    float* orow = out + (size_t)tk * N;
#pragma unroll
                    for (int j = 0; j < 4; j++) {
                        int ncol = n0 + wn + j * 16 + l16;
                        atomicAdd(&orow[ncol], w * acc[i][j][r]);
                    }
                }
            }
        }
    }
}

extern "C" void kernel_launch(void* const* d_in, const int* in_sizes, int n_in,
                              void* d_out, int out_size, void* d_ws, size_t ws_size,
                              hipStream_t stream) {
    const float* x      = (const float*)d_in[0];
    const float* logits = (const float*)d_in[1];
    const float* w1     = (const float*)d_in[2];
    const float* w2     = (const float*)d_in[3];
    float* out = (float*)d_out;
    char* ws = (char*)d_ws;

    // workspace layout
    const size_t OFF_CNT  = 0;
    const size_t OFF_BASE = 64;
    const size_t OFF_TOK  = 1024;
    const size_t OFF_WT   = OFF_TOK + (size_t)E_EXP * CAP * 4;
    const size_t OFF_XG   = 1u << 20;
    const size_t OFF_W1T  = OFF_XG + (size_t)T_TOKENS * H_DIM * 2;
    const size_t OFF_W2T  = OFF_W1T + (size_t)E_EXP * H_DIM * F_DIM * 2;
    const size_t OFF_G    = OFF_W2T + (size_t)E_EXP * H_DIM * F_DIM * 2;

    int* cnt  = (int*)(ws + OFF_CNT);
    int* base = (int*)(ws + OFF_BASE);
    int* tok  = (int*)(ws + OFF_TOK);
    float* wt = (float*)(ws + OFF_WT);
    unsigned short* xg  = (unsigned short*)(ws + OFF_XG);
    unsigned short* w1t = (unsigned short*)(ws + OFF_W1T);
    unsigned short* w2t = (unsigned short*)(ws + OFF_W2T);
    unsigned short* G   = (unsigned short*)(ws + OFF_G);

    hipMemsetAsync(d_out, 0, (size_t)out_size * sizeof(float), stream);
    hipMemsetAsync(cnt, 0, 64, stream);

    router_kernel<<<T_TOKENS / 256, 256, 0, stream>>>(logits, cnt, tok, wt);
    base_kernel<<<1, 64, 0, stream>>>(cnt, base);
    cvtx_kernel<<<(T_TOKENS * H_DIM / 4) / 256, 256, 0, stream>>>(x, xg);
    // w1 [E,H,F] -> w1t [E,F,H]
    tcvt_kernel<<<dim3(H_DIM / 64, F_DIM / 64, E_EXP), 256, 0, stream>>>(w1, w1t, H_DIM, F_DIM);
    // w2 [E,F,H] -> w2t [E,H,F]
    tcvt_kernel<<<dim3(F_DIM / 64, H_DIM / 64, E_EXP), 256, 0, stream>>>(w2, w2t, F_DIM, H_DIM);
    // GEMM1: [cnt_e x 1024] @ w1t -> gelu -> G [cnt_e x 4096] bf16
    gemm_kernel<1, 0><<<dim3(CAP / 128, F_DIM / 128, E_EXP), 256, 0, stream>>>(
        xg, w1t, H_DIM, F_DIM, cnt, base, tok, wt, G, nullptr);
    // GEMM2: G @ w2t -> weighted scatter-add into out
    gemm_kernel<0, 1><<<dim3(CAP / 128, H_DIM / 128, E_EXP), 256, 0, stream>>>(
        G, w2t, F_DIM, H_DIM, cnt, base, tok, wt, nullptr, out);
    (void)in_sizes; (void)n_in; (void)ws_size;
}

// Round 3
// 819.157 us; speedup vs baseline: 1.3600x; 1.2706x over previous
//
#include <hip/hip_runtime.h>

// Problem constants (B=4, S=2048, H=1024, E=8, F=4096, K=2)
#define T_TOKENS 8192
#define H_DIM 1024
#define E_EXP 8
#define F_DIM 4096
#define CAP 8192      // slot capacity per expert in tok/wt arrays
#define MT_TILES 32   // m-tiles per expert in GEMM grid (4096 rows >> 2048+50sigma)

typedef __attribute__((ext_vector_type(8))) short short8;
typedef __attribute__((ext_vector_type(8))) unsigned short ushort8;
typedef __attribute__((ext_vector_type(4))) float f32x4;

__device__ __forceinline__ unsigned short f2bf(float f) {
    unsigned int u = __float_as_uint(f);
    u += 0x7fffu + ((u >> 16) & 1u);   // round-to-nearest-even
    return (unsigned short)(u >> 16);
}

__device__ __forceinline__ float gelu_tanh(float x) {
    // jax.nn.gelu default (approximate=True)
    float z = 0.7978845608028654f * (x + 0.044715f * x * x * x);
    float t = 1.0f - 2.0f / (__expf(2.0f * z) + 1.0f);   // tanh(z)
    return 0.5f * x * (1.0f + t);
}

// async 16B global->LDS DMA (lane i of the wave lands at ldsbase + i*16)
__device__ __forceinline__ void gld16(const void* g, void* l) {
    __builtin_amdgcn_global_load_lds(
        (const __attribute__((address_space(1))) unsigned int*)g,
        (__attribute__((address_space(3))) unsigned int*)l,
        16, 0, 0);
}

// ---------------- router: top-2 + softmax over the 2 selected ----------------
__global__ void router_kernel(const float* __restrict__ logits,
                              int* __restrict__ cnt,
                              int* __restrict__ tok,
                              float* __restrict__ wt) {
    int t = blockIdx.x * 256 + threadIdx.x;
    if (t >= T_TOKENS) return;
    float l[E_EXP];
#pragma unroll
    for (int i = 0; i < E_EXP; i++) l[i] = logits[t * E_EXP + i];
    int i0 = 0; float s0 = l[0];
#pragma unroll
    for (int i = 1; i < E_EXP; i++) if (l[i] > s0) { s0 = l[i]; i0 = i; }
    int i1 = (i0 == 0) ? 1 : 0; float s1 = l[i1];
#pragma unroll
    for (int i = 0; i < E_EXP; i++) if (i != i0 && l[i] > s1) { s1 = l[i]; i1 = i; }
    float p0 = 1.0f / (1.0f + __expf(s1 - s0));
    float p1 = 1.0f - p0;
    int sl0 = atomicAdd(&cnt[i0], 1);
    tok[i0 * CAP + sl0] = t; wt[i0 * CAP + sl0] = p0;
    int sl1 = atomicAdd(&cnt[i1], 1);
    tok[i1 * CAP + sl1] = t; wt[i1 * CAP + sl1] = p1;
}

__global__ void base_kernel(const int* __restrict__ cnt, int* __restrict__ base) {
    if (threadIdx.x == 0) {
        int b = 0;
        for (int e = 0; e < E_EXP; e++) { base[e] = b; b += cnt[e]; }
    }
}

// ---------------- x fp32 -> bf16 ----------------
__global__ void cvtx_kernel(const float* __restrict__ x, unsigned short* __restrict__ xg) {
    int i = blockIdx.x * 256 + threadIdx.x;   // over T*H/4
    float4 v = ((const float4*)x)[i];
    ushort4 o;
    o.x = f2bf(v.x); o.y = f2bf(v.y); o.z = f2bf(v.z); o.w = f2bf(v.w);
    ((ushort4*)xg)[i] = o;
}

// ---------------- transpose + convert: in [M,N] fp32 -> out [N,M] bf16 (per expert z)
// 64x64 tile; float4 reads, ushort8 (16B) writes, ~2-way (free) LDS banking
__global__ void tcvt_kernel(const float* __restrict__ in, unsigned short* __restrict__ out,
                            int M, int N) {
    __shared__ float t[64][65];
    size_t eoff = (size_t)blockIdx.z * M * N;
    in += eoff; out += eoff;
    int r0 = blockIdx.x * 64, c0 = blockIdx.y * 64;
    int tid = threadIdx.x;
    int srow = tid >> 4;            // 0..15
    int scol = (tid & 15) * 4;
#pragma unroll
    for (int p = 0; p < 4; p++) {
        int row = p * 16 + srow;
        float4 v = *(const float4*)&in[(size_t)(r0 + row) * N + c0 + scol];
        t[row][scol + 0] = v.x; t[row][scol + 1] = v.y;
        t[row][scol + 2] = v.z; t[row][scol + 3] = v.w;
    }
    __syncthreads();
    int orow = tid >> 3;            // 0..31
    int ocb = (tid & 7) * 8;        // out col base (in-row index)
#pragma unroll
    for (int p = 0; p < 2; p++) {
        int r = p * 32 + orow;      // local out row (= in col)
        ushort8 o;
#pragma unroll
        for (int i = 0; i < 8; i++) o[i] = f2bf(t[ocb + i][r]);
        *(ushort8*)&out[(size_t)(c0 + r) * M + r0 + ocb] = o;
    }
}

// ---------------- grouped GEMM (m97 staging + XCD swizzle + BK=64) ----------------
// C[m,n] = sum_k A[m,k] * B[n,k]   (B pre-transposed, k contiguous)
// GATHER=1: A row m of expert e is xg[tok[e*CAP+m]]     (GEMM1)
// GATHER=0: A row m of expert e is G[base[e]+m]         (GEMM2)
// EPI=0: gelu -> bf16 G[(base+m)*N + n]
// EPI=1: atomicAdd(out[tok*N + n], wt * val)
// Swizzle: 1D grid; xcd = bid&7 owns n_tiles [xcd*NT8, (xcd+1)*NT8) -> B bands L2-resident.
template <int GATHER, int EPI, int NT8>
__global__ __launch_bounds__(256, 2)
void gemm_kernel(const unsigned short* __restrict__ Asrc,
                 const unsigned short* __restrict__ Bt,
                 int K, int N,
                 const int* __restrict__ cnt, const int* __restrict__ base,
                 const int* __restrict__ tok, const float* __restrict__ wt,
                 unsigned short* __restrict__ Gout, float* __restrict__ out) {
    int bid = blockIdx.x;
    int xcd = bid & 7;
    int q = bid >> 3;
    int nl = q % NT8;                 // n fast within XCD (NT8 is 4 or 1, compile-time)
    int q2 = q / NT8;
    int m_tile = q2 & (MT_TILES - 1);
    const int e = q2 >> 5;            // MT_TILES = 32
    const int n_tile = xcd * NT8 + nl;

    const int cnt_e = cnt[e];
    const int m0 = m_tile * 128;
    if (m0 >= cnt_e) return;
    const int base_e = base[e];
    const int n0 = n_tile * 128;
    const int tid = threadIdx.x;
    const int lane = tid & 63;
    const int wave = tid >> 6;
    const int quad = lane >> 4, l16 = lane & 15;
    const int wm = (wave & 1) * 64, wn = (wave >> 1) * 64;

    // BK=64 as two 32-k half tiles; each half keeps the wave-linear DMA layout
    __shared__ unsigned short As[2][128][32];
    __shared__ unsigned short Bs[2][128][32];

    const int srow = wave * 16 + (lane >> 2);   // row within 64-row group
    const int selem = (lane & 3) * 8;           // k elem within 32-k half
    const unsigned short* aptr[2];
    const unsigned short* bptr[2];
#pragma unroll
    for (int p = 0; p < 2; p++) {
        int gr = m0 + p * 64 + srow;
        if (gr > cnt_e - 1) gr = cnt_e - 1;     // tail clamp (epilogue guards)
        const unsigned short* arow;
        if (GATHER) arow = Asrc + (size_t)tok[e * CAP + gr] * K;
        else        arow = Asrc + (size_t)(base_e + gr) * K;
        aptr[p] = arow + selem;
        bptr[p] = Bt + (size_t)e * (size_t)N * K + (size_t)(n0 + p * 64 + srow) * K + selem;
    }
    unsigned short* alds0 = &As[0][wave * 16][0];
    unsigned short* alds1 = &As[0][64 + wave * 16][0];
    unsigned short* blds0 = &Bs[0][wave * 16][0];
    unsigned short* blds1 = &Bs[0][64 + wave * 16][0];
    const int HALF = 128 * 32;   // shorts per half tile

    f32x4 acc[4][4];
#pragma unroll
    for (int i = 0; i < 4; i++)
#pragma unroll
        for (int j = 0; j < 4; j++) acc[i][j] = (f32x4){0.f, 0.f, 0.f, 0.f};

    for (int k0 = 0; k0 < K; k0 += 64) {
#pragma unroll
        for (int sub = 0; sub < 2; sub++) {
            gld16(aptr[0] + k0 + sub * 32, alds0 + sub * HALF);
            gld16(aptr[1] + k0 + sub * 32, alds1 + sub * HALF);
            gld16(bptr[0] + k0 + sub * 32, blds0 + sub * HALF);
            gld16(bptr[1] + k0 + sub * 32, blds1 + sub * HALF);
        }
        __syncthreads();
#pragma unroll
        for (int sub = 0; sub < 2; sub++) {
            short8 af[4], bf[4];
#pragma unroll
            for (int i = 0; i < 4; i++)
                af[i] = *(const short8*)&As[sub][wm + i * 16 + l16][quad * 8];
#pragma unroll
            for (int j = 0; j < 4; j++)
                bf[j] = *(const short8*)&Bs[sub][wn + j * 16 + l16][quad * 8];
#pragma unroll
            for (int i = 0; i < 4; i++)
#pragma unroll
                for (int j = 0; j < 4; j++)
                    acc[i][j] = __builtin_amdgcn_mfma_f32_16x16x32_bf16(af[i], bf[j], acc[i][j], 0, 0, 0);
        }
        __syncthreads();
    }

    // epilogue: D row = quad*4 + reg, D col = l16 (within each 16x16 tile)
    if (EPI == 0) {
#pragma unroll
        for (int i = 0; i < 4; i++) {
            int lm = wm + i * 16 + quad * 4;
#pragma unroll
            for (int r = 0; r < 4; r++) {
                int gr = m0 + lm + r;
                if (gr < cnt_e) {
                    size_t rowoff = (size_t)(base_e + gr) * N;
#pragma unroll
                    for (int j = 0; j < 4; j++) {
                        int ncol = n0 + wn + j * 16 + l16;
                        Gout[rowoff + ncol] = f2bf(gelu_tanh(acc[i][j][r]));
                    }
                }
            }
        }
    } else {
#pragma unroll
        for (int i = 0; i < 4; i++) {
            int lm = wm + i * 16 + quad * 4;
#pragma unroll
            for (int r = 0; r < 4; r++) {
                int gr = m0 + lm + r;
                if (gr < cnt_e) {
                    int tk = tok[e * CAP + gr];
                    float w = wt[e * CAP + gr];
                    float* orow = out + (size_t)tk * N;
#pragma unroll
                    for (int j = 0; j < 4; j++) {
                        int ncol = n0 + wn + j * 16 + l16;
                        atomicAdd(&orow[ncol], w * acc[i][j][r]);
                    }
                }
            }
        }
    }
}

extern "C" void kernel_launch(void* const* d_in, const int* in_sizes, int n_in,
                              void* d_out, int out_size, void* d_ws, size_t ws_size,
                              hipStream_t stream) {
    const float* x      = (const float*)d_in[0];
    const float* logits = (const float*)d_in[1];
    const float* w1     = (const float*)d_in[2];
    const float* w2     = (const float*)d_in[3];
    float* out = (float*)d_out;
    char* ws = (char*)d_ws;

    // workspace layout
    const size_t OFF_CNT  = 0;
    const size_t OFF_BASE = 64;
    const size_t OFF_TOK  = 1024;
    const size_t OFF_WT   = OFF_TOK + (size_t)E_EXP * CAP * 4;
    const size_t OFF_XG   = 1u << 20;
    const size_t OFF_W1T  = OFF_XG + (size_t)T_TOKENS * H_DIM * 2;
    const size_t OFF_W2T  = OFF_W1T + (size_t)E_EXP * H_DIM * F_DIM * 2;
    const size_t OFF_G    = OFF_W2T + (size_t)E_EXP * H_DIM * F_DIM * 2;

    int* cnt  = (int*)(ws + OFF_CNT);
    int* base = (int*)(ws + OFF_BASE);
    int* tok  = (int*)(ws + OFF_TOK);
    float* wt = (float*)(ws + OFF_WT);
    unsigned short* xg  = (unsigned short*)(ws + OFF_XG);
    unsigned short* w1t = (unsigned short*)(ws + OFF_W1T);
    unsigned short* w2t = (unsigned short*)(ws + OFF_W2T);
    unsigned short* G   = (unsigned short*)(ws + OFF_G);

    hipMemsetAsync(d_out, 0, (size_t)out_size * sizeof(float), stream);
    hipMemsetAsync(cnt, 0, 64, stream);

    router_kernel<<<T_TOKENS / 256, 256, 0, stream>>>(logits, cnt, tok, wt);
    base_kernel<<<1, 64, 0, stream>>>(cnt, base);
    cvtx_kernel<<<(T_TOKENS * H_DIM / 4) / 256, 256, 0, stream>>>(x, xg);
    // w1 [E,H,F] -> w1t [E,F,H]
    tcvt_kernel<<<dim3(H_DIM / 64, F_DIM / 64, E_EXP), 256, 0, stream>>>(w1, w1t, H_DIM, F_DIM);
    // w2 [E,F,H] -> w2t [E,H,F]
    tcvt_kernel<<<dim3(F_DIM / 64, H_DIM / 64, E_EXP), 256, 0, stream>>>(w2, w2t, F_DIM, H_DIM);
    // GEMM1: [cnt_e x 1024] @ w1t -> gelu -> G [cnt_e x 4096] bf16   (NT=32, NT8=4)
    gemm_kernel<1, 0, 4><<<8 * 4 * MT_TILES * E_EXP, 256, 0, stream>>>(
        xg, w1t, H_DIM, F_DIM, cnt, base, tok, wt, G, nullptr);
    // GEMM2: G @ w2t -> weighted scatter-add into out                (NT=8, NT8=1)
    gemm_kernel<0, 1, 1><<<8 * 1 * MT_TILES * E_EXP, 256, 0, stream>>>(
        G, w2t, F_DIM, H_DIM, cnt, base, tok, wt, nullptr, out);
    (void)in_sizes; (void)n_in; (void)ws_size;
}

// Round 4
// 748.384 us; speedup vs baseline: 1.4886x; 1.0946x over previous
//
#include <hip/hip_runtime.h>

// Problem constants (B=4, S=2048, H=1024, E=8, F=4096, K=2)
#define T_TOKENS 8192
#define H_DIM 1024
#define E_EXP 8
#define F_DIM 4096
#define CAP 8192      // slot capacity per expert in tok/wt arrays
#define MT_TILES 32   // m-tiles per expert in GEMM grid

typedef __attribute__((ext_vector_type(8))) short short8;
typedef __attribute__((ext_vector_type(8))) unsigned short ushort8;
typedef __attribute__((ext_vector_type(4))) float f32x4;

__device__ __forceinline__ unsigned short f2bf(float f) {
    unsigned int u = __float_as_uint(f);
    u += 0x7fffu + ((u >> 16) & 1u);   // round-to-nearest-even
    return (unsigned short)(u >> 16);
}

__device__ __forceinline__ float gelu_tanh(float x) {
    // jax.nn.gelu default (approximate=True)
    float z = 0.7978845608028654f * (x + 0.044715f * x * x * x);
    float t = 1.0f - 2.0f / (__expf(2.0f * z) + 1.0f);   // tanh(z)
    return 0.5f * x * (1.0f + t);
}

// async 16B global->LDS DMA (lane i of the wave lands at ldsbase + i*16)
__device__ __forceinline__ void gld16(const void* g, void* l) {
    __builtin_amdgcn_global_load_lds(
        (const __attribute__((address_space(1))) unsigned int*)g,
        (__attribute__((address_space(3))) unsigned int*)l,
        16, 0, 0);
}

// ---------------- router: top-2 + softmax; block-aggregated slot assignment --------
__global__ void router_kernel(const float* __restrict__ logits,
                              int* __restrict__ cnt,
                              int* __restrict__ tok,
                              float* __restrict__ wt) {
    __shared__ int hcnt[E_EXP];
    __shared__ int hbase[E_EXP];
    int tid = threadIdx.x;
    if (tid < E_EXP) hcnt[tid] = 0;
    __syncthreads();
    int t = blockIdx.x * 256 + tid;
    float l[E_EXP];
#pragma unroll
    for (int i = 0; i < E_EXP; i++) l[i] = logits[t * E_EXP + i];
    int i0 = 0; float s0 = l[0];
#pragma unroll
    for (int i = 1; i < E_EXP; i++) if (l[i] > s0) { s0 = l[i]; i0 = i; }
    int i1 = (i0 == 0) ? 1 : 0; float s1 = l[i1];
#pragma unroll
    for (int i = 0; i < E_EXP; i++) if (i != i0 && l[i] > s1) { s1 = l[i]; i1 = i; }
    float p0 = 1.0f / (1.0f + __expf(s1 - s0));
    float p1 = 1.0f - p0;
    int lo0 = atomicAdd(&hcnt[i0], 1);   // LDS atomic (fast, 8 addrs)
    int lo1 = atomicAdd(&hcnt[i1], 1);
    __syncthreads();
    if (tid < E_EXP) hbase[tid] = atomicAdd(&cnt[tid], hcnt[tid]);  // 8 global atomics/block
    __syncthreads();
    int sl0 = hbase[i0] + lo0;
    tok[i0 * CAP + sl0] = t; wt[i0 * CAP + sl0] = p0;
    int sl1 = hbase[i1] + lo1;
    tok[i1 * CAP + sl1] = t; wt[i1 * CAP + sl1] = p1;
}

__global__ void base_kernel(const int* __restrict__ cnt, int* __restrict__ base) {
    if (threadIdx.x == 0) {
        int b = 0;
        for (int e = 0; e < E_EXP; e++) { base[e] = b; b += cnt[e]; }
    }
}

// ---------------- x fp32 -> bf16 ----------------
__global__ void cvtx_kernel(const float* __restrict__ x, unsigned short* __restrict__ xg) {
    int i = blockIdx.x * 256 + threadIdx.x;   // over T*H/4
    float4 v = ((const float4*)x)[i];
    ushort4 o;
    o.x = f2bf(v.x); o.y = f2bf(v.y); o.z = f2bf(v.z); o.w = f2bf(v.w);
    ((ushort4*)xg)[i] = o;
}

// ---------------- transpose + convert: in [M,N] fp32 -> out [N,M] bf16 (per expert z)
__global__ void tcvt_kernel(const float* __restrict__ in, unsigned short* __restrict__ out,
                            int M, int N) {
    __shared__ float t[64][65];
    size_t eoff = (size_t)blockIdx.z * M * N;
    in += eoff; out += eoff;
    int r0 = blockIdx.x * 64, c0 = blockIdx.y * 64;
    int tid = threadIdx.x;
    int srow = tid >> 4;            // 0..15
    int scol = (tid & 15) * 4;
#pragma unroll
    for (int p = 0; p < 4; p++) {
        int row = p * 16 + srow;
        float4 v = *(const float4*)&in[(size_t)(r0 + row) * N + c0 + scol];
        t[row][scol + 0] = v.x; t[row][scol + 1] = v.y;
        t[row][scol + 2] = v.z; t[row][scol + 3] = v.w;
    }
    __syncthreads();
    int orow = tid >> 3;            // 0..31
    int ocb = (tid & 7) * 8;        // out col base (in-row index)
#pragma unroll
    for (int p = 0; p < 2; p++) {
        int r = p * 32 + orow;      // local out row (= in col)
        ushort8 o;
#pragma unroll
        for (int i = 0; i < 8; i++) o[i] = f2bf(t[ocb + i][r]);
        *(ushort8*)&out[(size_t)(c0 + r) * M + r0 + ocb] = o;
    }
}

// ---------------- grouped GEMM (m97 staging + XCD partition + BK=64) ----------------
// C[m,n] = sum_k A[m,k] * B[n,k]   (B pre-transposed, k contiguous)
// GATHER=1: A row m of expert e is xg[tok[e*CAP+m]]     (GEMM1)
// GATHER=0: A row m of expert e is G[base[e]+m]         (GEMM2)
// EPI=0: gelu -> bf16 G[(base+m)*N + n]
// EPI=1: atomicAdd(out[tok*N + n], wt * val)
// Partition: xcd = bid&7. MC m-groups (xcd & (MC-1)), xcd/MC owns NT8 n-tiles.
// m-tiles interleaved by parity across groups for load balance.
template <int GATHER, int EPI, int NT8, int MC>
__global__ __launch_bounds__(256, 4)
void gemm_kernel(const unsigned short* __restrict__ Asrc,
                 const unsigned short* __restrict__ Bt,
                 int K, int N,
                 const int* __restrict__ cnt, const int* __restrict__ base,
                 const int* __restrict__ tok, const float* __restrict__ wt,
                 unsigned short* __restrict__ Gout, float* __restrict__ out) {
    int bid = blockIdx.x;
    int xcd = bid & 7;
    int q = bid >> 3;
    int nl = q % NT8;                       // n fastest within XCD (B band L2-hot)
    int q2 = q / NT8;
    const int MTG = MT_TILES / MC;          // m-tiles per group
    int mt = q2 % MTG;
    const int e = q2 / MTG;
    const int g = xcd & (MC - 1);
    const int n_tile = (xcd / MC) * NT8 + nl;
    const int m_tile = mt * MC + g;         // parity-interleaved

    const int cnt_e = cnt[e];
    const int m0 = m_tile * 128;
    if (m0 >= cnt_e) return;
    const int base_e = base[e];
    const int n0 = n_tile * 128;
    const int tid = threadIdx.x;
    const int lane = tid & 63;
    const int wave = tid >> 6;
    const int quad = lane >> 4, l16 = lane & 15;
    const int wm = (wave & 1) * 64, wn = (wave >> 1) * 64;

    // BK=64 as two 32-k half tiles; each half keeps the wave-linear DMA layout
    __shared__ unsigned short As[2][128][32];
    __shared__ unsigned short Bs[2][128][32];

    const int srow = wave * 16 + (lane >> 2);   // row within 64-row group
    const int selem = (lane & 3) * 8;           // k elem within 32-k half
    const unsigned short* aptr[2];
    const unsigned short* bptr[2];
#pragma unroll
    for (int p = 0; p < 2; p++) {
        int gr = m0 + p * 64 + srow;
        if (gr > cnt_e - 1) gr = cnt_e - 1;     // tail clamp (epilogue guards)
        const unsigned short* arow;
        if (GATHER) arow = Asrc + (size_t)tok[e * CAP + gr] * K;
        else        arow = Asrc + (size_t)(base_e + gr) * K;
        aptr[p] = arow + selem;
        bptr[p] = Bt + (size_t)e * (size_t)N * K + (size_t)(n0 + p * 64 + srow) * K + selem;
    }
    unsigned short* alds0 = &As[0][wave * 16][0];
    unsigned short* alds1 = &As[0][64 + wave * 16][0];
    unsigned short* blds0 = &Bs[0][wave * 16][0];
    unsigned short* blds1 = &Bs[0][64 + wave * 16][0];
    const int HALF = 128 * 32;   // shorts per half tile

    f32x4 acc[4][4];
#pragma unroll
    for (int i = 0; i < 4; i++)
#pragma unroll
        for (int j = 0; j < 4; j++) acc[i][j] = (f32x4){0.f, 0.f, 0.f, 0.f};

    for (int k0 = 0; k0 < K; k0 += 64) {
#pragma unroll
        for (int sub = 0; sub < 2; sub++) {
            gld16(aptr[0] + k0 + sub * 32, alds0 + sub * HALF);
            gld16(aptr[1] + k0 + sub * 32, alds1 + sub * HALF);
            gld16(bptr[0] + k0 + sub * 32, blds0 + sub * HALF);
            gld16(bptr[1] + k0 + sub * 32, blds1 + sub * HALF);
        }
        __syncthreads();
#pragma unroll
        for (int sub = 0; sub < 2; sub++) {
            short8 af[4], bf[4];
#pragma unroll
            for (int i = 0; i < 4; i++)
                af[i] = *(const short8*)&As[sub][wm + i * 16 + l16][quad * 8];
#pragma unroll
            for (int j = 0; j < 4; j++)
                bf[j] = *(const short8*)&Bs[sub][wn + j * 16 + l16][quad * 8];
#pragma unroll
            for (int i = 0; i < 4; i++)
#pragma unroll
                for (int j = 0; j < 4; j++)
                    acc[i][j] = __builtin_amdgcn_mfma_f32_16x16x32_bf16(af[i], bf[j], acc[i][j], 0, 0, 0);
        }
        __syncthreads();
    }

    // epilogue: D row = quad*4 + reg, D col = l16 (within each 16x16 tile)
    if (EPI == 0) {
#pragma unroll
        for (int i = 0; i < 4; i++) {
            int lm = wm + i * 16 + quad * 4;
#pragma unroll
            for (int r = 0; r < 4; r++) {
                int gr = m0 + lm + r;
                if (gr < cnt_e) {
                    size_t rowoff = (size_t)(base_e + gr) * N;
#pragma unroll
                    for (int j = 0; j < 4; j++) {
                        int ncol = n0 + wn + j * 16 + l16;
                        Gout[rowoff + ncol] = f2bf(gelu_tanh(acc[i][j][r]));
                    }
                }
            }
        }
    } else {
#pragma unroll
        for (int i = 0; i < 4; i++) {
            int lm = wm + i * 16 + quad * 4;
#pragma unroll
            for (int r = 0; r < 4; r++) {
                int gr = m0 + lm + r;
                if (gr < cnt_e) {
                    int tk = tok[e * CAP + gr];
                    float w = wt[e * CAP + gr];
                    float* orow = out + (size_t)tk * N;
#pragma unroll
                    for (int j = 0; j < 4; j++) {
                        int ncol = n0 + wn + j * 16 + l16;
                        atomicAdd(&orow[ncol], w * acc[i][j][r]);
                    }
                }
            }
        }
    }
}

extern "C" void kernel_launch(void* const* d_in, const int* in_sizes, int n_in,
                              void* d_out, int out_size, void* d_ws, size_t ws_size,
                              hipStream_t stream) {
    const float* x      = (const float*)d_in[0];
    const float* logits = (const float*)d_in[1];
    const float* w1     = (const float*)d_in[2];
    const float* w2     = (const float*)d_in[3];
    float* out = (float*)d_out;
    char* ws = (char*)d_ws;

    // workspace layout
    const size_t OFF_CNT  = 0;
    const size_t OFF_BASE = 64;
    const size_t OFF_TOK  = 1024;
    const size_t OFF_WT   = OFF_TOK + (size_t)E_EXP * CAP * 4;
    const size_t OFF_XG   = 1u << 20;
    const size_t OFF_W1T  = OFF_XG + (size_t)T_TOKENS * H_DIM * 2;
    const size_t OFF_W2T  = OFF_W1T + (size_t)E_EXP * H_DIM * F_DIM * 2;
    const size_t OFF_G    = OFF_W2T + (size_t)E_EXP * H_DIM * F_DIM * 2;

    int* cnt  = (int*)(ws + OFF_CNT);
    int* base = (int*)(ws + OFF_BASE);
    int* tok  = (int*)(ws + OFF_TOK);
    float* wt = (float*)(ws + OFF_WT);
    unsigned short* xg  = (unsigned short*)(ws + OFF_XG);
    unsigned short* w1t = (unsigned short*)(ws + OFF_W1T);
    unsigned short* w2t = (unsigned short*)(ws + OFF_W2T);
    unsigned short* G   = (unsigned short*)(ws + OFF_G);

    hipMemsetAsync(d_out, 0, (size_t)out_size * sizeof(float), stream);
    hipMemsetAsync(cnt, 0, 64, stream);

    router_kernel<<<T_TOKENS / 256, 256, 0, stream>>>(logits, cnt, tok, wt);
    base_kernel<<<1, 64, 0, stream>>>(cnt, base);
    cvtx_kernel<<<(T_TOKENS * H_DIM / 4) / 256, 256, 0, stream>>>(x, xg);
    // w1 [E,H,F] -> w1t [E,F,H]
    tcvt_kernel<<<dim3(H_DIM / 64, F_DIM / 64, E_EXP), 256, 0, stream>>>(w1, w1t, H_DIM, F_DIM);
    // w2 [E,F,H] -> w2t [E,H,F]
    tcvt_kernel<<<dim3(F_DIM / 64, H_DIM / 64, E_EXP), 256, 0, stream>>>(w2, w2t, F_DIM, H_DIM);
    // GEMM1: MC=1, NT8=4  (8 XCD x 4 n-tiles = 32 n-tiles of F=4096)
    gemm_kernel<1, 0, 4, 1><<<8 * 4 * MT_TILES * E_EXP, 256, 0, stream>>>(
        xg, w1t, H_DIM, F_DIM, cnt, base, tok, wt, G, nullptr);
    // GEMM2: MC=2, NT8=2  (2 m-groups x 4 XCD x 2 n-tiles = 8 n-tiles of H=1024)
    gemm_kernel<0, 1, 2, 2><<<8 * 2 * (MT_TILES / 2) * E_EXP, 256, 0, stream>>>(
        G, w2t, F_DIM, H_DIM, cnt, base, tok, wt, nullptr, out);
    (void)in_sizes; (void)n_in; (void)ws_size;
}